// Round 6
// baseline (1381.768 us; speedup 1.0000x reference)
//
#include <hip/hip_runtime.h>
#include <hip/hip_bf16.h>
#include <stdint.h>

#define N_NODES 100000
#define N_EDGES 3200000
#define ALPHA   0.1f

typedef __attribute__((ext_vector_type(8))) short v8s;   // 8 x bf16
typedef __attribute__((ext_vector_type(4))) float f32x4; // MFMA acc

__device__ __forceinline__ uint32_t bf16_rne(float f) {
    uint32_t u = __float_as_uint(f);
    return (u + 0x7FFFu + ((u >> 16) & 1u)) >> 16;
}
__device__ __forceinline__ float bf16_f32(uint32_t b) { return __uint_as_float(b << 16); }

// ---------------------------------------------------------------------------
// W1 [256][512] fp32 -> A-fragment-ordered hi/lo bf16 chunks in global.
// ---------------------------------------------------------------------------
__global__ __launch_bounds__(256) void w1_frag_kernel(
    const float* __restrict__ W1, uint4* __restrict__ W1f)
{
    int tid = blockIdx.x * 256 + threadIdx.x;   // 16384
    int ks = tid >> 10, T = (tid >> 6) & 15, l = tid & 63;
    int row = T * 16 + (l & 15);
    int kb  = ks * 32 + (l >> 4) * 8;
    const float* src = W1 + (size_t)row * 512 + kb;
    float4 f0 = *(const float4*)(src);
    float4 f1 = *(const float4*)(src + 4);
    float f[8] = {f0.x, f0.y, f0.z, f0.w, f1.x, f1.y, f1.z, f1.w};
    uint32_t hi[8], lo[8];
#pragma unroll
    for (int j = 0; j < 8; ++j) {
        hi[j] = bf16_rne(f[j]);
        lo[j] = bf16_rne(f[j] - bf16_f32(hi[j]));
    }
    uint4 H = make_uint4(hi[0] | (hi[1] << 16), hi[2] | (hi[3] << 16),
                         hi[4] | (hi[5] << 16), hi[6] | (hi[7] << 16));
    uint4 L = make_uint4(lo[0] | (lo[1] << 16), lo[2] | (lo[3] << 16),
                         lo[4] | (lo[5] << 16), lo[6] | (lo[7] << 16));
    size_t base = ((size_t)(ks * 2) * 16 + T) * 64 + l;
    W1f[base]        = H;
    W1f[base + 1024] = L;   // p=1 plane
}

// ---------------------------------------------------------------------------
// MLP: h = relu(x@W1^T+b1)@W2^T+b2 via MFMA 16x16x32 bf16 hi/lo split.
// R6: launch_bounds (256,4) -> 4 blocks/CU (LDS 33280*4=133KB fits 160KB,
// VGPR 116 <= 128). Doubled TLP hides the staging-barrier latency that
// intra-wave prefetch (R5) could not.
// ---------------------------------------------------------------------------
__global__ __launch_bounds__(256, 4) void mlp_kernel(
    const float* __restrict__ x, const uint4* __restrict__ W1f,
    const float* __restrict__ b1, const float* __restrict__ W2,
    const float* __restrict__ b2, const float* __restrict__ dinv,
    float* __restrict__ h, float* __restrict__ hs, int n)
{
    __shared__ __align__(16) char smem[33280];
    char*  xs   = smem;                    // K-loop: hi plane 4096 + lo plane 4096
    float* W2s  = (float*)smem;            // epilogue: [16][260] = 16640 B
    float* part = (float*)(smem + 16640);  // epilogue: [4][64][16] = 16384 B

    const int tid = threadIdx.x;
    const int w = tid >> 6, l = tid & 63;
    const int l15 = l & 15, q = l >> 4;
    const int row0 = blockIdx.x * 64;

    const int s_l15 = tid & 15;
    const int s_seg = (tid >> 4) & 3;
    const int s_u   = tid >> 6;
    const int s_grow = row0 + s_u * 16 + s_l15;
    const bool s_ok = (s_grow < n);
    const float* xrow = x + (size_t)s_grow * 512 + s_seg * 8;

    f32x4 acc[4][4];
#pragma unroll
    for (int mt = 0; mt < 4; ++mt)
#pragma unroll
        for (int nt = 0; nt < 4; ++nt) acc[mt][nt] = (f32x4){0.f, 0.f, 0.f, 0.f};

    // prefetch ks = 0 chunk
    float4 f0 = make_float4(0.f, 0.f, 0.f, 0.f), f1 = f0;
    if (s_ok) {
        f0 = *(const float4*)(xrow);
        f1 = *(const float4*)(xrow + 4);
    }

    for (int ks = 0; ks < 16; ++ks) {
        uint4 aHu[4], aLu[4];
#pragma unroll
        for (int mt = 0; mt < 4; ++mt) {
            size_t cidx = ((size_t)(ks * 2) * 16 + (w * 4 + mt)) * 64 + l;
            aHu[mt] = W1f[cidx];
            aLu[mt] = W1f[cidx + 1024];
        }
        // convert the prefetched chunk
        float f[8] = {f0.x, f0.y, f0.z, f0.w, f1.x, f1.y, f1.z, f1.w};
        uint32_t hi[8], lo[8];
#pragma unroll
        for (int j = 0; j < 8; ++j) {
            hi[j] = bf16_rne(f[j]);
            lo[j] = bf16_rne(f[j] - bf16_f32(hi[j]));
        }
        uint4 H = make_uint4(hi[0] | (hi[1] << 16), hi[2] | (hi[3] << 16),
                             hi[4] | (hi[5] << 16), hi[6] | (hi[7] << 16));
        uint4 L = make_uint4(lo[0] | (lo[1] << 16), lo[2] | (lo[3] << 16),
                             lo[4] | (lo[5] << 16), lo[6] | (lo[7] << 16));
        __syncthreads();
        *(uint4*)(xs +        s_u * 1024 + (s_seg * 16 + s_l15) * 16) = H;
        *(uint4*)(xs + 4096 + s_u * 1024 + (s_seg * 16 + s_l15) * 16) = L;
        __syncthreads();

        // issue next-chunk loads now; the MFMA phase below hides the latency
        if (ks < 15 && s_ok) {
            const float* xp = xrow + (ks + 1) * 32;
            f0 = *(const float4*)(xp);
            f1 = *(const float4*)(xp + 4);
        }

        v8s bH[4], bL[4];
#pragma unroll
        for (int nt = 0; nt < 4; ++nt) {
            bH[nt] = *(v8s*)(xs +        nt * 1024 + l * 16);
            bL[nt] = *(v8s*)(xs + 4096 + nt * 1024 + l * 16);
        }
#pragma unroll
        for (int mt = 0; mt < 4; ++mt) {
            v8s aH = *(v8s*)&aHu[mt];
            v8s aL = *(v8s*)&aLu[mt];
#pragma unroll
            for (int nt = 0; nt < 4; ++nt) {
                f32x4 c = acc[mt][nt];
                c = __builtin_amdgcn_mfma_f32_16x16x32_bf16(aH, bH[nt], c, 0, 0, 0);
                c = __builtin_amdgcn_mfma_f32_16x16x32_bf16(aH, bL[nt], c, 0, 0, 0);
                c = __builtin_amdgcn_mfma_f32_16x16x32_bf16(aL, bH[nt], c, 0, 0, 0);
                c = __builtin_amdgcn_mfma_f32_16x16x32_bf16(aL, bL[nt], c, 0, 0, 0);
                acc[mt][nt] = c;
            }
        }
    }

#pragma unroll
    for (int mt = 0; mt < 4; ++mt) {
        float4 bv = *(const float4*)(b1 + w * 64 + mt * 16 + q * 4);
#pragma unroll
        for (int nt = 0; nt < 4; ++nt) {
            acc[mt][nt][0] = fmaxf(acc[mt][nt][0] + bv.x, 0.f);
            acc[mt][nt][1] = fmaxf(acc[mt][nt][1] + bv.y, 0.f);
            acc[mt][nt][2] = fmaxf(acc[mt][nt][2] + bv.z, 0.f);
            acc[mt][nt][3] = fmaxf(acc[mt][nt][3] + bv.w, 0.f);
        }
    }

    __syncthreads();
    {
        int c = tid >> 4, k16 = (tid & 15) * 16;
#pragma unroll
        for (int i = 0; i < 4; ++i)
            *(float4*)(W2s + c * 260 + k16 + i * 4) =
                *(const float4*)(W2 + c * 256 + k16 + i * 4);
    }
    __syncthreads();

#pragma unroll
    for (int c4 = 0; c4 < 4; ++c4) {
        float p2[4][4];
#pragma unroll
        for (int nt = 0; nt < 4; ++nt)
#pragma unroll
            for (int cc = 0; cc < 4; ++cc) p2[nt][cc] = 0.f;
#pragma unroll
        for (int mt = 0; mt < 4; ++mt)
#pragma unroll
            for (int cc = 0; cc < 4; ++cc) {
                float4 wv = *(float4*)(W2s + (c4 * 4 + cc) * 260 + w * 64 + mt * 16 + q * 4);
#pragma unroll
                for (int nt = 0; nt < 4; ++nt)
                    p2[nt][cc] += acc[mt][nt][0] * wv.x + acc[mt][nt][1] * wv.y +
                                  acc[mt][nt][2] * wv.z + acc[mt][nt][3] * wv.w;
            }
#pragma unroll
        for (int nt = 0; nt < 4; ++nt)
#pragma unroll
            for (int cc = 0; cc < 4; ++cc) {
                p2[nt][cc] += __shfl_xor(p2[nt][cc], 16);
                p2[nt][cc] += __shfl_xor(p2[nt][cc], 32);
            }
        if (q == c4) {
#pragma unroll
            for (int nt = 0; nt < 4; ++nt)
                *(float4*)(part + ((w * 64 + nt * 16 + l15) << 4) + c4 * 4) =
                    make_float4(p2[nt][0], p2[nt][1], p2[nt][2], p2[nt][3]);
        }
    }
    __syncthreads();
    {
        int node = tid >> 2, c4 = (tid & 3) * 4;
        float4 s = make_float4(0.f, 0.f, 0.f, 0.f);
#pragma unroll
        for (int ww = 0; ww < 4; ++ww) {
            float4 v = *(float4*)(part + ((ww * 64 + node) << 4) + c4);
            s.x += v.x; s.y += v.y; s.z += v.z; s.w += v.w;
        }
        float4 bv = *(const float4*)(b2 + c4);
        int grow = row0 + node;
        if (grow < n) {
            float4 hv = make_float4(s.x + bv.x, s.y + bv.y, s.z + bv.z, s.w + bv.w);
            *(float4*)(h + (size_t)grow * 16 + c4) = hv;
            float di = dinv[grow];
            *(float4*)(hs + (size_t)grow * 16 + c4) =
                make_float4(di * hv.x, di * hv.y, di * hv.z, di * hv.w);
        }
    }
}

// ---------------------------------------------------------------------------
// CSR build
// ---------------------------------------------------------------------------
__global__ void hist_kernel(const int* __restrict__ dst, int* __restrict__ cnt, int e)
{
    int i = blockIdx.x * blockDim.x + threadIdx.x;
    if (i < e) atomicAdd(&cnt[dst[i]], 1);
}

// dinv from REAL degree; padded (mult-of-4) counts for CSR; zero dummy zs rows.
// R6: pad 16 -> 4. Padded lines 4.7M -> ~3.4M (-27% gather traffic; prop is
// at the random-gather line-throughput ceiling, so traffic ~ time).
__global__ void dinv_kernel(const int* __restrict__ cnt, float* __restrict__ dinv,
                            int* __restrict__ pcnt,
                            float* __restrict__ zsA_dummy, float* __restrict__ zsB_dummy,
                            int n)
{
    int i = blockIdx.x * blockDim.x + threadIdx.x;
    if (i < n) {
        int c = cnt[i];
        dinv[i] = rsqrtf((float)c + 1.0f);  // +1 self-loop
        pcnt[i] = (c + 3) & ~3;
    }
    if (i < 16) { zsA_dummy[i] = 0.0f; zsB_dummy[i] = 0.0f; }
}

// fill csr pad region with the dummy node index
__global__ void fill_kernel(int4* __restrict__ p, int v, int cnt4)
{
    int i = blockIdx.x * blockDim.x + threadIdx.x;
    if (i < cnt4) p[i] = make_int4(v, v, v, v);
}

// multi-block exclusive scan over pcnt (3 phases), covers i <= n
__global__ __launch_bounds__(256) void scan1_kernel(
    const int* __restrict__ pcnt, int* __restrict__ row_loc,
    int* __restrict__ bsum, int n)
{
    __shared__ int sm[256];
    int i = blockIdx.x * 256 + threadIdx.x;
    int v = (i < n) ? pcnt[i] : 0;
    sm[threadIdx.x] = v;
    __syncthreads();
#pragma unroll
    for (int off = 1; off < 256; off <<= 1) {
        int t = (threadIdx.x >= off) ? sm[threadIdx.x - off] : 0;
        __syncthreads();
        sm[threadIdx.x] += t;
        __syncthreads();
    }
    if (i <= n) row_loc[i] = sm[threadIdx.x] - v;
    if (threadIdx.x == 255) bsum[blockIdx.x] = sm[255];
}

__global__ __launch_bounds__(512) void scan2_kernel(
    const int* __restrict__ bsum, int* __restrict__ boff, int nb)
{
    __shared__ int sm[512];
    int i = threadIdx.x;
    int v = (i < nb) ? bsum[i] : 0;
    sm[i] = v;
    __syncthreads();
#pragma unroll
    for (int off = 1; off < 512; off <<= 1) {
        int t = (i >= off) ? sm[i - off] : 0;
        __syncthreads();
        sm[i] += t;
        __syncthreads();
    }
    if (i < nb) boff[i] = sm[i] - v;
}

__global__ void scan3_kernel(int* __restrict__ row_st, const int* __restrict__ boff,
                             int* __restrict__ cursor, int n)
{
    int i = blockIdx.x * blockDim.x + threadIdx.x;
    if (i <= n) {
        int r = row_st[i] + boff[i >> 8];
        row_st[i] = r;
        if (i < n) cursor[i] = r;
    }
}

// ---------------------------------------------------------------------------
// XCD-windowed scatter: block b = chunk (b>>3) x dst-window (b&7).
// Writes only the 4B src index (dst implied by CSR row). Edge order within a
// row is nondeterministic (atomics) -- prop compensates with fp64 accum.
// ---------------------------------------------------------------------------
#define SC_CHUNK 2048
__global__ __launch_bounds__(256) void scatter8_kernel(
    const int* __restrict__ src, const int* __restrict__ dst,
    int* __restrict__ cursor, int* __restrict__ csr_s, int e)
{
    const int w    = blockIdx.x & 7;
    const int base = (blockIdx.x >> 3) * SC_CHUNK;
    const int wlo  = w * (N_NODES / 8);
    const int whi  = wlo + (N_NODES / 8);
#pragma unroll
    for (int t = 0; t < SC_CHUNK / 256; ++t) {
        int i = base + t * 256 + threadIdx.x;
        if (i < e) {
            int d = dst[i];
            if (d >= wlo && d < whi) {
                int s = src[i];
                int pos = atomicAdd(&cursor[d], 1);
                csr_s[pos] = s;
            }
        }
    }
}

// ---------------------------------------------------------------------------
// Node-parallel pull, 16 lanes/node (4 subs x 4 class-lanes), rows padded to
// a multiple of 4. The sub-cyclic loop (start sub*4, stride 32 + single-group
// tail) covers any mult-of-4 row exactly; only tail iterations diverge.
// fp64 accumulation keeps the sum order-independent (CSR order is
// nondeterministic from the atomic scatter).
// ---------------------------------------------------------------------------
__global__ __launch_bounds__(256) void prop_kernel(
    const int* __restrict__ csr_s, const int* __restrict__ row_st,
    const float* __restrict__ dinv, const float* __restrict__ zs_in,
    const float* __restrict__ hmat, float* __restrict__ out,
    int n, int is_last)
{
    const int t = threadIdx.x;
    const int d = blockIdx.x * 16 + (t >> 4);
    if (d >= n) return;
    const int lane16 = t & 15;
    const int sub = lane16 >> 2;
    const int f4 = (lane16 & 3) * 4;
    const int rs = row_st[d], re = row_st[d + 1];

    double Sx = 0.0, Sy = 0.0, Sz = 0.0, Sw = 0.0;
    int j = rs + sub * 4;
    for (; j + 16 < re; j += 32) {
        int4 s0 = *(const int4*)(csr_s + j);
        int4 s1 = *(const int4*)(csr_s + j + 16);
        const float4 a0 = *(const float4*)(zs_in + (size_t)s0.x * 16 + f4);
        const float4 b0 = *(const float4*)(zs_in + (size_t)s0.y * 16 + f4);
        const float4 c0 = *(const float4*)(zs_in + (size_t)s0.z * 16 + f4);
        const float4 e0 = *(const float4*)(zs_in + (size_t)s0.w * 16 + f4);
        const float4 a1 = *(const float4*)(zs_in + (size_t)s1.x * 16 + f4);
        const float4 b1 = *(const float4*)(zs_in + (size_t)s1.y * 16 + f4);
        const float4 c1 = *(const float4*)(zs_in + (size_t)s1.z * 16 + f4);
        const float4 e1 = *(const float4*)(zs_in + (size_t)s1.w * 16 + f4);
        Sx += (((double)a0.x + (double)b0.x) + ((double)c0.x + (double)e0.x))
            + (((double)a1.x + (double)b1.x) + ((double)c1.x + (double)e1.x));
        Sy += (((double)a0.y + (double)b0.y) + ((double)c0.y + (double)e0.y))
            + (((double)a1.y + (double)b1.y) + ((double)c1.y + (double)e1.y));
        Sz += (((double)a0.z + (double)b0.z) + ((double)c0.z + (double)e0.z))
            + (((double)a1.z + (double)b1.z) + ((double)c1.z + (double)e1.z));
        Sw += (((double)a0.w + (double)b0.w) + ((double)c0.w + (double)e0.w))
            + (((double)a1.w + (double)b1.w) + ((double)c1.w + (double)e1.w));
    }
    if (j < re) {
        int4 s0 = *(const int4*)(csr_s + j);
        const float4 a0 = *(const float4*)(zs_in + (size_t)s0.x * 16 + f4);
        const float4 b0 = *(const float4*)(zs_in + (size_t)s0.y * 16 + f4);
        const float4 c0 = *(const float4*)(zs_in + (size_t)s0.z * 16 + f4);
        const float4 e0 = *(const float4*)(zs_in + (size_t)s0.w * 16 + f4);
        Sx += ((double)a0.x + (double)b0.x) + ((double)c0.x + (double)e0.x);
        Sy += ((double)a0.y + (double)b0.y) + ((double)c0.y + (double)e0.y);
        Sz += ((double)a0.z + (double)b0.z) + ((double)c0.z + (double)e0.z);
        Sw += ((double)a0.w + (double)b0.w) + ((double)c0.w + (double)e0.w);
    }

    // combine the 4 sub partial sums (all 16 lanes end with the full sum)
    Sx += __shfl_xor(Sx, 4); Sy += __shfl_xor(Sy, 4);
    Sz += __shfl_xor(Sz, 4); Sw += __shfl_xor(Sw, 4);
    Sx += __shfl_xor(Sx, 8); Sy += __shfl_xor(Sy, 8);
    Sz += __shfl_xor(Sz, 8); Sw += __shfl_xor(Sw, 8);

    // self-loop contribution
    const float4 self = *(const float4*)(zs_in + (size_t)d * 16 + f4);
    Sx += (double)self.x; Sy += (double)self.y;
    Sz += (double)self.z; Sw += (double)self.w;
    float4 S = make_float4((float)Sx, (float)Sy, (float)Sz, (float)Sw);

    const float di = dinv[d];
    const float4 hv = *(const float4*)(hmat + (size_t)d * 16 + f4);
    float4 zn;
    zn.x = fmaf(1.0f - ALPHA, di * S.x, ALPHA * hv.x);
    zn.y = fmaf(1.0f - ALPHA, di * S.y, ALPHA * hv.y);
    zn.z = fmaf(1.0f - ALPHA, di * S.z, ALPHA * hv.z);
    zn.w = fmaf(1.0f - ALPHA, di * S.w, ALPHA * hv.w);
    if (!is_last) {
        if (sub == 0)
            *(float4*)(out + (size_t)d * 16 + f4) =
                make_float4(di * zn.x, di * zn.y, di * zn.z, di * zn.w);
    } else {
        float m = fmaxf(fmaxf(zn.x, zn.y), fmaxf(zn.z, zn.w));
        m = fmaxf(m, __shfl_xor(m, 1));
        m = fmaxf(m, __shfl_xor(m, 2));
        float ss = expf(zn.x - m) + expf(zn.y - m) + expf(zn.z - m) + expf(zn.w - m);
        ss += __shfl_xor(ss, 1);
        ss += __shfl_xor(ss, 2);
        float ls = logf(ss);
        if (sub == 0)
            *(float4*)(out + (size_t)d * 16 + f4) =
                make_float4(zn.x - m - ls, zn.y - m - ls, zn.z - m - ls, zn.w - m - ls);
    }
}

// ---------------------------------------------------------------------------
extern "C" void kernel_launch(void* const* d_in, const int* in_sizes, int n_in,
                              void* d_out, int out_size, void* d_ws, size_t ws_size,
                              hipStream_t stream)
{
    const float* x  = (const float*)d_in[0];
    const float* W1 = (const float*)d_in[1];
    const float* b1 = (const float*)d_in[2];
    const float* W2 = (const float*)d_in[3];
    const float* b2 = (const float*)d_in[4];
    const int*   ei = (const int*)d_in[5];

    const int N = N_NODES;
    const int E = N_EDGES;
    const int EP_MAX = 3500000;                 // >= E + 3*N worst-case padded (pad-4)
    const int* srcp = ei;
    const int* dstp = ei + E;

    float* ws = (float*)d_ws;
    float* h       = ws;                        // 1,600,000 f
    float* ZSA     = ws + 1600000;              // 1,600,016 f (row N = dummy zeros)
    float* ZSB     = ws + 3200016;              // 1,600,016 f (starts as hs)
    float* dinv    = ws + 4800032;              // 100,000 f
    int*   row_st  = (int*)(ws + 4900032);      // 100,001 i (pad 100004)
    int*   csr_s   = (int*)(ws + 5000036);      // up to 3,500,000 x 4B
    // transient overlays (dead before mlp writes h):
    int*   cnt     = (int*)(ws);                // 100,000
    int*   cursor  = (int*)(ws + 100000);       // 100,000
    int*   bsum    = (int*)(ws + 200000);       // 512
    int*   boff    = (int*)(ws + 200512);       // 512
    int*   pcnt    = (int*)(ws + 201024);       // 100,000
    uint4* W1f     = (uint4*)(ws + 1600000);    // in ZSA region (dead before step 0)
    float* zsA_dummy = ZSA + (size_t)N * 16;
    float* zsB_dummy = ZSB + (size_t)N * 16;

    const int NB_SCAN = (N + 255) / 256;        // 391 (covers i <= N)

    hipMemsetAsync(cnt, 0, (size_t)N * sizeof(int), stream);
    hist_kernel<<<(E + 255) / 256, 256, 0, stream>>>(dstp, cnt, E);
    dinv_kernel<<<(N + 255) / 256, 256, 0, stream>>>(cnt, dinv, pcnt,
                                                     zsA_dummy, zsB_dummy, N);
    fill_kernel<<<(EP_MAX / 4 + 255) / 256, 256, 0, stream>>>((int4*)csr_s, N, EP_MAX / 4);
    scan1_kernel<<<NB_SCAN, 256, 0, stream>>>(pcnt, row_st, bsum, N);
    scan2_kernel<<<1, 512, 0, stream>>>(bsum, boff, NB_SCAN);
    scan3_kernel<<<(N + 256) / 256, 256, 0, stream>>>(row_st, boff, cursor, N);
    {
        const int nchunks = (E + SC_CHUNK - 1) / SC_CHUNK;   // 1563
        scatter8_kernel<<<nchunks * 8, 256, 0, stream>>>(srcp, dstp, cursor, csr_s, E);
    }
    w1_frag_kernel<<<64, 256, 0, stream>>>(W1, W1f);
    mlp_kernel<<<(N + 63) / 64, 256, 0, stream>>>(x, W1f, b1, W2, b2, dinv, h, ZSB, N);

    const int NB_PROP = (N + 15) / 16;   // 6250 blocks, 16 nodes/block
    for (int k = 0; k < 10; ++k) {
        const int last = (k == 9) ? 1 : 0;
        const float* zin = (k == 0) ? ZSB : ((k & 1) ? ZSA : ZSB);
        float* zo = last ? (float*)d_out : ((k & 1) ? ZSB : ZSA);
        prop_kernel<<<NB_PROP, 256, 0, stream>>>(csr_s, row_st, dinv, zin, h, zo,
                                                 N, last);
    }
}

// Round 7
// 990.032 us; speedup vs baseline: 1.3957x; 1.3957x over previous
//
#include <hip/hip_runtime.h>
#include <hip/hip_bf16.h>
#include <stdint.h>

#define N_NODES 100000
#define N_EDGES 3200000
#define ALPHA   0.1f

typedef __attribute__((ext_vector_type(8))) short v8s;   // 8 x bf16
typedef __attribute__((ext_vector_type(4))) float f32x4; // MFMA acc

__device__ __forceinline__ uint32_t bf16_rne(float f) {
    uint32_t u = __float_as_uint(f);
    return (u + 0x7FFFu + ((u >> 16) & 1u)) >> 16;
}
__device__ __forceinline__ float bf16_f32(uint32_t b) { return __uint_as_float(b << 16); }

// ---------------------------------------------------------------------------
// W1 [256][512] fp32 -> A-fragment-ordered hi/lo bf16 chunks in global.
// ---------------------------------------------------------------------------
__global__ __launch_bounds__(256) void w1_frag_kernel(
    const float* __restrict__ W1, uint4* __restrict__ W1f)
{
    int tid = blockIdx.x * 256 + threadIdx.x;   // 16384
    int ks = tid >> 10, T = (tid >> 6) & 15, l = tid & 63;
    int row = T * 16 + (l & 15);
    int kb  = ks * 32 + (l >> 4) * 8;
    const float* src = W1 + (size_t)row * 512 + kb;
    float4 f0 = *(const float4*)(src);
    float4 f1 = *(const float4*)(src + 4);
    float f[8] = {f0.x, f0.y, f0.z, f0.w, f1.x, f1.y, f1.z, f1.w};
    uint32_t hi[8], lo[8];
#pragma unroll
    for (int j = 0; j < 8; ++j) {
        hi[j] = bf16_rne(f[j]);
        lo[j] = bf16_rne(f[j] - bf16_f32(hi[j]));
    }
    uint4 H = make_uint4(hi[0] | (hi[1] << 16), hi[2] | (hi[3] << 16),
                         hi[4] | (hi[5] << 16), hi[6] | (hi[7] << 16));
    uint4 L = make_uint4(lo[0] | (lo[1] << 16), lo[2] | (lo[3] << 16),
                         lo[4] | (lo[5] << 16), lo[6] | (lo[7] << 16));
    size_t base = ((size_t)(ks * 2) * 16 + T) * 64 + l;
    W1f[base]        = H;
    W1f[base + 1024] = L;   // p=1 plane
}

// ---------------------------------------------------------------------------
// MLP: h = relu(x@W1^T+b1)@W2^T+b2 via MFMA 16x16x32 bf16 hi/lo split.
// R7: back to (256,2). R6's (256,4) capped the UNIFIED VGPR+AGPR budget at
// 128 < 116+64 -> accumulator spill (FETCH 107->723MB, 164->555us).
// ---------------------------------------------------------------------------
__global__ __launch_bounds__(256, 2) void mlp_kernel(
    const float* __restrict__ x, const uint4* __restrict__ W1f,
    const float* __restrict__ b1, const float* __restrict__ W2,
    const float* __restrict__ b2, const float* __restrict__ dinv,
    float* __restrict__ h, float* __restrict__ hs, int n)
{
    __shared__ __align__(16) char smem[33280];
    char*  xs   = smem;                    // K-loop: hi plane 4096 + lo plane 4096
    float* W2s  = (float*)smem;            // epilogue: [16][260] = 16640 B
    float* part = (float*)(smem + 16640);  // epilogue: [4][64][16] = 16384 B

    const int tid = threadIdx.x;
    const int w = tid >> 6, l = tid & 63;
    const int l15 = l & 15, q = l >> 4;
    const int row0 = blockIdx.x * 64;

    const int s_l15 = tid & 15;
    const int s_seg = (tid >> 4) & 3;
    const int s_u   = tid >> 6;
    const int s_grow = row0 + s_u * 16 + s_l15;
    const bool s_ok = (s_grow < n);
    const float* xrow = x + (size_t)s_grow * 512 + s_seg * 8;

    f32x4 acc[4][4];
#pragma unroll
    for (int mt = 0; mt < 4; ++mt)
#pragma unroll
        for (int nt = 0; nt < 4; ++nt) acc[mt][nt] = (f32x4){0.f, 0.f, 0.f, 0.f};

    // prefetch ks = 0 chunk
    float4 f0 = make_float4(0.f, 0.f, 0.f, 0.f), f1 = f0;
    if (s_ok) {
        f0 = *(const float4*)(xrow);
        f1 = *(const float4*)(xrow + 4);
    }

    for (int ks = 0; ks < 16; ++ks) {
        uint4 aHu[4], aLu[4];
#pragma unroll
        for (int mt = 0; mt < 4; ++mt) {
            size_t cidx = ((size_t)(ks * 2) * 16 + (w * 4 + mt)) * 64 + l;
            aHu[mt] = W1f[cidx];
            aLu[mt] = W1f[cidx + 1024];
        }
        // convert the prefetched chunk
        float f[8] = {f0.x, f0.y, f0.z, f0.w, f1.x, f1.y, f1.z, f1.w};
        uint32_t hi[8], lo[8];
#pragma unroll
        for (int j = 0; j < 8; ++j) {
            hi[j] = bf16_rne(f[j]);
            lo[j] = bf16_rne(f[j] - bf16_f32(hi[j]));
        }
        uint4 H = make_uint4(hi[0] | (hi[1] << 16), hi[2] | (hi[3] << 16),
                             hi[4] | (hi[5] << 16), hi[6] | (hi[7] << 16));
        uint4 L = make_uint4(lo[0] | (lo[1] << 16), lo[2] | (lo[3] << 16),
                             lo[4] | (lo[5] << 16), lo[6] | (lo[7] << 16));
        __syncthreads();
        *(uint4*)(xs +        s_u * 1024 + (s_seg * 16 + s_l15) * 16) = H;
        *(uint4*)(xs + 4096 + s_u * 1024 + (s_seg * 16 + s_l15) * 16) = L;
        __syncthreads();

        // issue next-chunk loads now; the MFMA phase below hides the latency
        if (ks < 15 && s_ok) {
            const float* xp = xrow + (ks + 1) * 32;
            f0 = *(const float4*)(xp);
            f1 = *(const float4*)(xp + 4);
        }

        v8s bH[4], bL[4];
#pragma unroll
        for (int nt = 0; nt < 4; ++nt) {
            bH[nt] = *(v8s*)(xs +        nt * 1024 + l * 16);
            bL[nt] = *(v8s*)(xs + 4096 + nt * 1024 + l * 16);
        }
#pragma unroll
        for (int mt = 0; mt < 4; ++mt) {
            v8s aH = *(v8s*)&aHu[mt];
            v8s aL = *(v8s*)&aLu[mt];
#pragma unroll
            for (int nt = 0; nt < 4; ++nt) {
                f32x4 c = acc[mt][nt];
                c = __builtin_amdgcn_mfma_f32_16x16x32_bf16(aH, bH[nt], c, 0, 0, 0);
                c = __builtin_amdgcn_mfma_f32_16x16x32_bf16(aH, bL[nt], c, 0, 0, 0);
                c = __builtin_amdgcn_mfma_f32_16x16x32_bf16(aL, bH[nt], c, 0, 0, 0);
                c = __builtin_amdgcn_mfma_f32_16x16x32_bf16(aL, bL[nt], c, 0, 0, 0);
                acc[mt][nt] = c;
            }
        }
    }

#pragma unroll
    for (int mt = 0; mt < 4; ++mt) {
        float4 bv = *(const float4*)(b1 + w * 64 + mt * 16 + q * 4);
#pragma unroll
        for (int nt = 0; nt < 4; ++nt) {
            acc[mt][nt][0] = fmaxf(acc[mt][nt][0] + bv.x, 0.f);
            acc[mt][nt][1] = fmaxf(acc[mt][nt][1] + bv.y, 0.f);
            acc[mt][nt][2] = fmaxf(acc[mt][nt][2] + bv.z, 0.f);
            acc[mt][nt][3] = fmaxf(acc[mt][nt][3] + bv.w, 0.f);
        }
    }

    __syncthreads();
    {
        int c = tid >> 4, k16 = (tid & 15) * 16;
#pragma unroll
        for (int i = 0; i < 4; ++i)
            *(float4*)(W2s + c * 260 + k16 + i * 4) =
                *(const float4*)(W2 + c * 256 + k16 + i * 4);
    }
    __syncthreads();

#pragma unroll
    for (int c4 = 0; c4 < 4; ++c4) {
        float p2[4][4];
#pragma unroll
        for (int nt = 0; nt < 4; ++nt)
#pragma unroll
            for (int cc = 0; cc < 4; ++cc) p2[nt][cc] = 0.f;
#pragma unroll
        for (int mt = 0; mt < 4; ++mt)
#pragma unroll
            for (int cc = 0; cc < 4; ++cc) {
                float4 wv = *(float4*)(W2s + (c4 * 4 + cc) * 260 + w * 64 + mt * 16 + q * 4);
#pragma unroll
                for (int nt = 0; nt < 4; ++nt)
                    p2[nt][cc] += acc[mt][nt][0] * wv.x + acc[mt][nt][1] * wv.y +
                                  acc[mt][nt][2] * wv.z + acc[mt][nt][3] * wv.w;
            }
#pragma unroll
        for (int nt = 0; nt < 4; ++nt)
#pragma unroll
            for (int cc = 0; cc < 4; ++cc) {
                p2[nt][cc] += __shfl_xor(p2[nt][cc], 16);
                p2[nt][cc] += __shfl_xor(p2[nt][cc], 32);
            }
        if (q == c4) {
#pragma unroll
            for (int nt = 0; nt < 4; ++nt)
                *(float4*)(part + ((w * 64 + nt * 16 + l15) << 4) + c4 * 4) =
                    make_float4(p2[nt][0], p2[nt][1], p2[nt][2], p2[nt][3]);
        }
    }
    __syncthreads();
    {
        int node = tid >> 2, c4 = (tid & 3) * 4;
        float4 s = make_float4(0.f, 0.f, 0.f, 0.f);
#pragma unroll
        for (int ww = 0; ww < 4; ++ww) {
            float4 v = *(float4*)(part + ((ww * 64 + node) << 4) + c4);
            s.x += v.x; s.y += v.y; s.z += v.z; s.w += v.w;
        }
        float4 bv = *(const float4*)(b2 + c4);
        int grow = row0 + node;
        if (grow < n) {
            float4 hv = make_float4(s.x + bv.x, s.y + bv.y, s.z + bv.z, s.w + bv.w);
            *(float4*)(h + (size_t)grow * 16 + c4) = hv;
            float di = dinv[grow];
            *(float4*)(hs + (size_t)grow * 16 + c4) =
                make_float4(di * hv.x, di * hv.y, di * hv.z, di * hv.w);
        }
    }
}

// ---------------------------------------------------------------------------
// CSR build
// ---------------------------------------------------------------------------
__global__ void hist_kernel(const int* __restrict__ dst, int* __restrict__ cnt, int e)
{
    int i = blockIdx.x * blockDim.x + threadIdx.x;
    if (i < e) atomicAdd(&cnt[dst[i]], 1);
}

// dinv from REAL degree; padded (mult-of-4) counts for CSR; zero dummy zs rows.
__global__ void dinv_kernel(const int* __restrict__ cnt, float* __restrict__ dinv,
                            int* __restrict__ pcnt,
                            float* __restrict__ zsA_dummy, float* __restrict__ zsB_dummy,
                            int n)
{
    int i = blockIdx.x * blockDim.x + threadIdx.x;
    if (i < n) {
        int c = cnt[i];
        dinv[i] = rsqrtf((float)c + 1.0f);  // +1 self-loop
        pcnt[i] = (c + 3) & ~3;
    }
    if (i < 16) { zsA_dummy[i] = 0.0f; zsB_dummy[i] = 0.0f; }
}

// fill csr pad region with the dummy node index
__global__ void fill_kernel(int4* __restrict__ p, int v, int cnt4)
{
    int i = blockIdx.x * blockDim.x + threadIdx.x;
    if (i < cnt4) p[i] = make_int4(v, v, v, v);
}

// multi-block exclusive scan over pcnt (3 phases), covers i <= n
__global__ __launch_bounds__(256) void scan1_kernel(
    const int* __restrict__ pcnt, int* __restrict__ row_loc,
    int* __restrict__ bsum, int n)
{
    __shared__ int sm[256];
    int i = blockIdx.x * 256 + threadIdx.x;
    int v = (i < n) ? pcnt[i] : 0;
    sm[threadIdx.x] = v;
    __syncthreads();
#pragma unroll
    for (int off = 1; off < 256; off <<= 1) {
        int t = (threadIdx.x >= off) ? sm[threadIdx.x - off] : 0;
        __syncthreads();
        sm[threadIdx.x] += t;
        __syncthreads();
    }
    if (i <= n) row_loc[i] = sm[threadIdx.x] - v;
    if (threadIdx.x == 255) bsum[blockIdx.x] = sm[255];
}

__global__ __launch_bounds__(512) void scan2_kernel(
    const int* __restrict__ bsum, int* __restrict__ boff, int nb)
{
    __shared__ int sm[512];
    int i = threadIdx.x;
    int v = (i < nb) ? bsum[i] : 0;
    sm[i] = v;
    __syncthreads();
#pragma unroll
    for (int off = 1; off < 512; off <<= 1) {
        int t = (i >= off) ? sm[i - off] : 0;
        __syncthreads();
        sm[i] += t;
        __syncthreads();
    }
    if (i < nb) boff[i] = sm[i] - v;
}

__global__ void scan3_kernel(int* __restrict__ row_st, const int* __restrict__ boff,
                             int* __restrict__ cursor, int n)
{
    int i = blockIdx.x * blockDim.x + threadIdx.x;
    if (i <= n) {
        int r = row_st[i] + boff[i >> 8];
        row_st[i] = r;
        if (i < n) cursor[i] = r;
    }
}

// ---------------------------------------------------------------------------
// XCD-windowed scatter: block b = chunk (b>>3) x dst-window (b&7).
// Writes only the 4B src index (dst implied by CSR row). Edge order within a
// row is nondeterministic (atomics) -- prop compensates with fp64 accum.
// ---------------------------------------------------------------------------
#define SC_CHUNK 2048
__global__ __launch_bounds__(256) void scatter8_kernel(
    const int* __restrict__ src, const int* __restrict__ dst,
    int* __restrict__ cursor, int* __restrict__ csr_s, int e)
{
    const int w    = blockIdx.x & 7;
    const int base = (blockIdx.x >> 3) * SC_CHUNK;
    const int wlo  = w * (N_NODES / 8);
    const int whi  = wlo + (N_NODES / 8);
#pragma unroll
    for (int t = 0; t < SC_CHUNK / 256; ++t) {
        int i = base + t * 256 + threadIdx.x;
        if (i < e) {
            int d = dst[i];
            if (d >= wlo && d < whi) {
                int s = src[i];
                int pos = atomicAdd(&cursor[d], 1);
                csr_s[pos] = s;
            }
        }
    }
}

// ---------------------------------------------------------------------------
// Node-parallel pull, 16 lanes/node (4 subs x 4 class-lanes), rows padded to
// a multiple of 4. R7: epilogue loads (dinv, self, hmat) hoisted BEFORE the
// edge loop -- they are address-ready at entry, so their ~500cy latency
// overlaps the gather chain instead of serializing after the shuffles.
// self folds into the sub-0 accumulator init (gives the load an early use).
// fp64 accum keeps the sum order-independent (CSR order nondeterministic).
// ---------------------------------------------------------------------------
__global__ __launch_bounds__(256) void prop_kernel(
    const int* __restrict__ csr_s, const int* __restrict__ row_st,
    const float* __restrict__ dinv, const float* __restrict__ zs_in,
    const float* __restrict__ hmat, float* __restrict__ out,
    int n, int is_last)
{
    const int t = threadIdx.x;
    const int d = blockIdx.x * 16 + (t >> 4);
    if (d >= n) return;
    const int lane16 = t & 15;
    const int sub = lane16 >> 2;
    const int f4 = (lane16 & 3) * 4;
    const int rs = row_st[d], re = row_st[d + 1];

    // early-issued epilogue loads (latency hidden under the edge loop)
    const float di = dinv[d];
    const float4 self = *(const float4*)(zs_in + (size_t)d * 16 + f4);
    const float4 hv   = *(const float4*)(hmat  + (size_t)d * 16 + f4);

    // self-loop contribution seeds sub 0's accumulator (early use, no branch)
    const double w0 = (sub == 0) ? 1.0 : 0.0;
    double Sx = w0 * (double)self.x, Sy = w0 * (double)self.y;
    double Sz = w0 * (double)self.z, Sw = w0 * (double)self.w;

    int j = rs + sub * 4;
    for (; j + 16 < re; j += 32) {
        int4 s0 = *(const int4*)(csr_s + j);
        int4 s1 = *(const int4*)(csr_s + j + 16);
        const float4 a0 = *(const float4*)(zs_in + (size_t)s0.x * 16 + f4);
        const float4 b0 = *(const float4*)(zs_in + (size_t)s0.y * 16 + f4);
        const float4 c0 = *(const float4*)(zs_in + (size_t)s0.z * 16 + f4);
        const float4 e0 = *(const float4*)(zs_in + (size_t)s0.w * 16 + f4);
        const float4 a1 = *(const float4*)(zs_in + (size_t)s1.x * 16 + f4);
        const float4 b1 = *(const float4*)(zs_in + (size_t)s1.y * 16 + f4);
        const float4 c1 = *(const float4*)(zs_in + (size_t)s1.z * 16 + f4);
        const float4 e1 = *(const float4*)(zs_in + (size_t)s1.w * 16 + f4);
        Sx += (((double)a0.x + (double)b0.x) + ((double)c0.x + (double)e0.x))
            + (((double)a1.x + (double)b1.x) + ((double)c1.x + (double)e1.x));
        Sy += (((double)a0.y + (double)b0.y) + ((double)c0.y + (double)e0.y))
            + (((double)a1.y + (double)b1.y) + ((double)c1.y + (double)e1.y));
        Sz += (((double)a0.z + (double)b0.z) + ((double)c0.z + (double)e0.z))
            + (((double)a1.z + (double)b1.z) + ((double)c1.z + (double)e1.z));
        Sw += (((double)a0.w + (double)b0.w) + ((double)c0.w + (double)e0.w))
            + (((double)a1.w + (double)b1.w) + ((double)c1.w + (double)e1.w));
    }
    if (j < re) {
        int4 s0 = *(const int4*)(csr_s + j);
        const float4 a0 = *(const float4*)(zs_in + (size_t)s0.x * 16 + f4);
        const float4 b0 = *(const float4*)(zs_in + (size_t)s0.y * 16 + f4);
        const float4 c0 = *(const float4*)(zs_in + (size_t)s0.z * 16 + f4);
        const float4 e0 = *(const float4*)(zs_in + (size_t)s0.w * 16 + f4);
        Sx += ((double)a0.x + (double)b0.x) + ((double)c0.x + (double)e0.x);
        Sy += ((double)a0.y + (double)b0.y) + ((double)c0.y + (double)e0.y);
        Sz += ((double)a0.z + (double)b0.z) + ((double)c0.z + (double)e0.z);
        Sw += ((double)a0.w + (double)b0.w) + ((double)c0.w + (double)e0.w);
    }

    // combine the 4 sub partial sums (all 16 lanes end with the full sum)
    Sx += __shfl_xor(Sx, 4); Sy += __shfl_xor(Sy, 4);
    Sz += __shfl_xor(Sz, 4); Sw += __shfl_xor(Sw, 4);
    Sx += __shfl_xor(Sx, 8); Sy += __shfl_xor(Sy, 8);
    Sz += __shfl_xor(Sz, 8); Sw += __shfl_xor(Sw, 8);

    float4 S = make_float4((float)Sx, (float)Sy, (float)Sz, (float)Sw);

    float4 zn;
    zn.x = fmaf(1.0f - ALPHA, di * S.x, ALPHA * hv.x);
    zn.y = fmaf(1.0f - ALPHA, di * S.y, ALPHA * hv.y);
    zn.z = fmaf(1.0f - ALPHA, di * S.z, ALPHA * hv.z);
    zn.w = fmaf(1.0f - ALPHA, di * S.w, ALPHA * hv.w);
    if (!is_last) {
        if (sub == 0)
            *(float4*)(out + (size_t)d * 16 + f4) =
                make_float4(di * zn.x, di * zn.y, di * zn.z, di * zn.w);
    } else {
        float m = fmaxf(fmaxf(zn.x, zn.y), fmaxf(zn.z, zn.w));
        m = fmaxf(m, __shfl_xor(m, 1));
        m = fmaxf(m, __shfl_xor(m, 2));
        float ss = expf(zn.x - m) + expf(zn.y - m) + expf(zn.z - m) + expf(zn.w - m);
        ss += __shfl_xor(ss, 1);
        ss += __shfl_xor(ss, 2);
        float ls = logf(ss);
        if (sub == 0)
            *(float4*)(out + (size_t)d * 16 + f4) =
                make_float4(zn.x - m - ls, zn.y - m - ls, zn.z - m - ls, zn.w - m - ls);
    }
}

// ---------------------------------------------------------------------------
extern "C" void kernel_launch(void* const* d_in, const int* in_sizes, int n_in,
                              void* d_out, int out_size, void* d_ws, size_t ws_size,
                              hipStream_t stream)
{
    const float* x  = (const float*)d_in[0];
    const float* W1 = (const float*)d_in[1];
    const float* b1 = (const float*)d_in[2];
    const float* W2 = (const float*)d_in[3];
    const float* b2 = (const float*)d_in[4];
    const int*   ei = (const int*)d_in[5];

    const int N = N_NODES;
    const int E = N_EDGES;
    const int EP_MAX = 3500000;                 // >= E + 3*N worst-case padded (pad-4)
    const int* srcp = ei;
    const int* dstp = ei + E;

    float* ws = (float*)d_ws;
    float* h       = ws;                        // 1,600,000 f
    float* ZSA     = ws + 1600000;              // 1,600,016 f (row N = dummy zeros)
    float* ZSB     = ws + 3200016;              // 1,600,016 f (starts as hs)
    float* dinv    = ws + 4800032;              // 100,000 f
    int*   row_st  = (int*)(ws + 4900032);      // 100,001 i (pad 100004)
    int*   csr_s   = (int*)(ws + 5000036);      // up to 3,500,000 x 4B
    // transient overlays (dead before mlp writes h):
    int*   cnt     = (int*)(ws);                // 100,000
    int*   cursor  = (int*)(ws + 100000);       // 100,000
    int*   bsum    = (int*)(ws + 200000);       // 512
    int*   boff    = (int*)(ws + 200512);       // 512
    int*   pcnt    = (int*)(ws + 201024);       // 100,000
    uint4* W1f     = (uint4*)(ws + 1600000);    // in ZSA region (dead before step 0)
    float* zsA_dummy = ZSA + (size_t)N * 16;
    float* zsB_dummy = ZSB + (size_t)N * 16;

    const int NB_SCAN = (N + 255) / 256;        // 391 (covers i <= N)

    hipMemsetAsync(cnt, 0, (size_t)N * sizeof(int), stream);
    hist_kernel<<<(E + 255) / 256, 256, 0, stream>>>(dstp, cnt, E);
    dinv_kernel<<<(N + 255) / 256, 256, 0, stream>>>(cnt, dinv, pcnt,
                                                     zsA_dummy, zsB_dummy, N);
    fill_kernel<<<(EP_MAX / 4 + 255) / 256, 256, 0, stream>>>((int4*)csr_s, N, EP_MAX / 4);
    scan1_kernel<<<NB_SCAN, 256, 0, stream>>>(pcnt, row_st, bsum, N);
    scan2_kernel<<<1, 512, 0, stream>>>(bsum, boff, NB_SCAN);
    scan3_kernel<<<(N + 256) / 256, 256, 0, stream>>>(row_st, boff, cursor, N);
    {
        const int nchunks = (E + SC_CHUNK - 1) / SC_CHUNK;   // 1563
        scatter8_kernel<<<nchunks * 8, 256, 0, stream>>>(srcp, dstp, cursor, csr_s, E);
    }
    w1_frag_kernel<<<64, 256, 0, stream>>>(W1, W1f);
    mlp_kernel<<<(N + 63) / 64, 256, 0, stream>>>(x, W1f, b1, W2, b2, dinv, h, ZSB, N);

    const int NB_PROP = (N + 15) / 16;   // 6250 blocks, 16 nodes/block
    for (int k = 0; k < 10; ++k) {
        const int last = (k == 9) ? 1 : 0;
        const float* zin = (k == 0) ? ZSB : ((k & 1) ? ZSA : ZSB);
        float* zo = last ? (float*)d_out : ((k & 1) ? ZSB : ZSA);
        prop_kernel<<<NB_PROP, 256, 0, stream>>>(csr_s, row_st, dinv, zin, h, zo,
                                                 N, last);
    }
}

// Round 8
// 885.721 us; speedup vs baseline: 1.5600x; 1.1178x over previous
//
#include <hip/hip_runtime.h>
#include <hip/hip_bf16.h>
#include <stdint.h>

#define N_NODES 100000
#define N_EDGES 3200000
#define ALPHA   0.1f

typedef __attribute__((ext_vector_type(8))) short v8s;   // 8 x bf16
typedef __attribute__((ext_vector_type(4))) float f32x4; // MFMA acc

__device__ __forceinline__ uint32_t bf16_rne(float f) {
    uint32_t u = __float_as_uint(f);
    return (u + 0x7FFFu + ((u >> 16) & 1u)) >> 16;
}
__device__ __forceinline__ float bf16_f32(uint32_t b) { return __uint_as_float(b << 16); }
// unpack a bf16 pair packed as lo | (hi<<16)
__device__ __forceinline__ float blo(uint32_t p) { return __uint_as_float(p << 16); }
__device__ __forceinline__ float bhi(uint32_t p) { return __uint_as_float(p & 0xffff0000u); }

// ---------------------------------------------------------------------------
// W1 [256][512] fp32 -> A-fragment-ordered hi/lo bf16 chunks in global.
// ---------------------------------------------------------------------------
__global__ __launch_bounds__(256) void w1_frag_kernel(
    const float* __restrict__ W1, uint4* __restrict__ W1f)
{
    int tid = blockIdx.x * 256 + threadIdx.x;   // 16384
    int ks = tid >> 10, T = (tid >> 6) & 15, l = tid & 63;
    int row = T * 16 + (l & 15);
    int kb  = ks * 32 + (l >> 4) * 8;
    const float* src = W1 + (size_t)row * 512 + kb;
    float4 f0 = *(const float4*)(src);
    float4 f1 = *(const float4*)(src + 4);
    float f[8] = {f0.x, f0.y, f0.z, f0.w, f1.x, f1.y, f1.z, f1.w};
    uint32_t hi[8], lo[8];
#pragma unroll
    for (int j = 0; j < 8; ++j) {
        hi[j] = bf16_rne(f[j]);
        lo[j] = bf16_rne(f[j] - bf16_f32(hi[j]));
    }
    uint4 H = make_uint4(hi[0] | (hi[1] << 16), hi[2] | (hi[3] << 16),
                         hi[4] | (hi[5] << 16), hi[6] | (hi[7] << 16));
    uint4 L = make_uint4(lo[0] | (lo[1] << 16), lo[2] | (lo[3] << 16),
                         lo[4] | (lo[5] << 16), lo[6] | (lo[7] << 16));
    size_t base = ((size_t)(ks * 2) * 16 + T) * 64 + l;
    W1f[base]        = H;
    W1f[base + 1024] = L;   // p=1 plane
}

// ---------------------------------------------------------------------------
// MLP: h = relu(x@W1^T+b1)@W2^T+b2 via MFMA 16x16x32 bf16 hi/lo split.
// (256,2): R6 showed (256,4) caps the UNIFIED VGPR+AGPR budget -> acc spill.
// R8: hs (= dinv*h seed state) now stored as bf16 rows (32B/node).
// ---------------------------------------------------------------------------
__global__ __launch_bounds__(256, 2) void mlp_kernel(
    const float* __restrict__ x, const uint4* __restrict__ W1f,
    const float* __restrict__ b1, const float* __restrict__ W2,
    const float* __restrict__ b2, const float* __restrict__ dinv,
    float* __restrict__ h, uint16_t* __restrict__ hs, int n)
{
    __shared__ __align__(16) char smem[33280];
    char*  xs   = smem;                    // K-loop: hi plane 4096 + lo plane 4096
    float* W2s  = (float*)smem;            // epilogue: [16][260] = 16640 B
    float* part = (float*)(smem + 16640);  // epilogue: [4][64][16] = 16384 B

    const int tid = threadIdx.x;
    const int w = tid >> 6, l = tid & 63;
    const int l15 = l & 15, q = l >> 4;
    const int row0 = blockIdx.x * 64;

    const int s_l15 = tid & 15;
    const int s_seg = (tid >> 4) & 3;
    const int s_u   = tid >> 6;
    const int s_grow = row0 + s_u * 16 + s_l15;
    const bool s_ok = (s_grow < n);
    const float* xrow = x + (size_t)s_grow * 512 + s_seg * 8;

    f32x4 acc[4][4];
#pragma unroll
    for (int mt = 0; mt < 4; ++mt)
#pragma unroll
        for (int nt = 0; nt < 4; ++nt) acc[mt][nt] = (f32x4){0.f, 0.f, 0.f, 0.f};

    // prefetch ks = 0 chunk
    float4 f0 = make_float4(0.f, 0.f, 0.f, 0.f), f1 = f0;
    if (s_ok) {
        f0 = *(const float4*)(xrow);
        f1 = *(const float4*)(xrow + 4);
    }

    for (int ks = 0; ks < 16; ++ks) {
        uint4 aHu[4], aLu[4];
#pragma unroll
        for (int mt = 0; mt < 4; ++mt) {
            size_t cidx = ((size_t)(ks * 2) * 16 + (w * 4 + mt)) * 64 + l;
            aHu[mt] = W1f[cidx];
            aLu[mt] = W1f[cidx + 1024];
        }
        // convert the prefetched chunk
        float f[8] = {f0.x, f0.y, f0.z, f0.w, f1.x, f1.y, f1.z, f1.w};
        uint32_t hi[8], lo[8];
#pragma unroll
        for (int j = 0; j < 8; ++j) {
            hi[j] = bf16_rne(f[j]);
            lo[j] = bf16_rne(f[j] - bf16_f32(hi[j]));
        }
        uint4 H = make_uint4(hi[0] | (hi[1] << 16), hi[2] | (hi[3] << 16),
                             hi[4] | (hi[5] << 16), hi[6] | (hi[7] << 16));
        uint4 L = make_uint4(lo[0] | (lo[1] << 16), lo[2] | (lo[3] << 16),
                             lo[4] | (lo[5] << 16), lo[6] | (lo[7] << 16));
        __syncthreads();
        *(uint4*)(xs +        s_u * 1024 + (s_seg * 16 + s_l15) * 16) = H;
        *(uint4*)(xs + 4096 + s_u * 1024 + (s_seg * 16 + s_l15) * 16) = L;
        __syncthreads();

        // issue next-chunk loads now; the MFMA phase below hides the latency
        if (ks < 15 && s_ok) {
            const float* xp = xrow + (ks + 1) * 32;
            f0 = *(const float4*)(xp);
            f1 = *(const float4*)(xp + 4);
        }

        v8s bH[4], bL[4];
#pragma unroll
        for (int nt = 0; nt < 4; ++nt) {
            bH[nt] = *(v8s*)(xs +        nt * 1024 + l * 16);
            bL[nt] = *(v8s*)(xs + 4096 + nt * 1024 + l * 16);
        }
#pragma unroll
        for (int mt = 0; mt < 4; ++mt) {
            v8s aH = *(v8s*)&aHu[mt];
            v8s aL = *(v8s*)&aLu[mt];
#pragma unroll
            for (int nt = 0; nt < 4; ++nt) {
                f32x4 c = acc[mt][nt];
                c = __builtin_amdgcn_mfma_f32_16x16x32_bf16(aH, bH[nt], c, 0, 0, 0);
                c = __builtin_amdgcn_mfma_f32_16x16x32_bf16(aH, bL[nt], c, 0, 0, 0);
                c = __builtin_amdgcn_mfma_f32_16x16x32_bf16(aL, bH[nt], c, 0, 0, 0);
                c = __builtin_amdgcn_mfma_f32_16x16x32_bf16(aL, bL[nt], c, 0, 0, 0);
                acc[mt][nt] = c;
            }
        }
    }

#pragma unroll
    for (int mt = 0; mt < 4; ++mt) {
        float4 bv = *(const float4*)(b1 + w * 64 + mt * 16 + q * 4);
#pragma unroll
        for (int nt = 0; nt < 4; ++nt) {
            acc[mt][nt][0] = fmaxf(acc[mt][nt][0] + bv.x, 0.f);
            acc[mt][nt][1] = fmaxf(acc[mt][nt][1] + bv.y, 0.f);
            acc[mt][nt][2] = fmaxf(acc[mt][nt][2] + bv.z, 0.f);
            acc[mt][nt][3] = fmaxf(acc[mt][nt][3] + bv.w, 0.f);
        }
    }

    __syncthreads();
    {
        int c = tid >> 4, k16 = (tid & 15) * 16;
#pragma unroll
        for (int i = 0; i < 4; ++i)
            *(float4*)(W2s + c * 260 + k16 + i * 4) =
                *(const float4*)(W2 + c * 256 + k16 + i * 4);
    }
    __syncthreads();

#pragma unroll
    for (int c4 = 0; c4 < 4; ++c4) {
        float p2[4][4];
#pragma unroll
        for (int nt = 0; nt < 4; ++nt)
#pragma unroll
            for (int cc = 0; cc < 4; ++cc) p2[nt][cc] = 0.f;
#pragma unroll
        for (int mt = 0; mt < 4; ++mt)
#pragma unroll
            for (int cc = 0; cc < 4; ++cc) {
                float4 wv = *(float4*)(W2s + (c4 * 4 + cc) * 260 + w * 64 + mt * 16 + q * 4);
#pragma unroll
                for (int nt = 0; nt < 4; ++nt)
                    p2[nt][cc] += acc[mt][nt][0] * wv.x + acc[mt][nt][1] * wv.y +
                                  acc[mt][nt][2] * wv.z + acc[mt][nt][3] * wv.w;
            }
#pragma unroll
        for (int nt = 0; nt < 4; ++nt)
#pragma unroll
            for (int cc = 0; cc < 4; ++cc) {
                p2[nt][cc] += __shfl_xor(p2[nt][cc], 16);
                p2[nt][cc] += __shfl_xor(p2[nt][cc], 32);
            }
        if (q == c4) {
#pragma unroll
            for (int nt = 0; nt < 4; ++nt)
                *(float4*)(part + ((w * 64 + nt * 16 + l15) << 4) + c4 * 4) =
                    make_float4(p2[nt][0], p2[nt][1], p2[nt][2], p2[nt][3]);
        }
    }
    __syncthreads();
    {
        int node = tid >> 2, c4 = (tid & 3) * 4;
        float4 s = make_float4(0.f, 0.f, 0.f, 0.f);
#pragma unroll
        for (int ww = 0; ww < 4; ++ww) {
            float4 v = *(float4*)(part + ((ww * 64 + node) << 4) + c4);
            s.x += v.x; s.y += v.y; s.z += v.z; s.w += v.w;
        }
        float4 bv = *(const float4*)(b2 + c4);
        int grow = row0 + node;
        if (grow < n) {
            float4 hv = make_float4(s.x + bv.x, s.y + bv.y, s.z + bv.z, s.w + bv.w);
            *(float4*)(h + (size_t)grow * 16 + c4) = hv;
            float di = dinv[grow];
            uint32_t p0 = bf16_rne(di * hv.x) | (bf16_rne(di * hv.y) << 16);
            uint32_t p1 = bf16_rne(di * hv.z) | (bf16_rne(di * hv.w) << 16);
            *(uint2*)(hs + (size_t)grow * 16 + c4) = make_uint2(p0, p1);
        }
    }
}

// ---------------------------------------------------------------------------
// CSR build
// ---------------------------------------------------------------------------
__global__ void hist_kernel(const int* __restrict__ dst, int* __restrict__ cnt, int e)
{
    int i = blockIdx.x * blockDim.x + threadIdx.x;
    if (i < e) atomicAdd(&cnt[dst[i]], 1);
}

// dinv from REAL degree; padded (mult-of-4) counts for CSR; zero dummy zs rows.
__global__ void dinv_kernel(const int* __restrict__ cnt, float* __restrict__ dinv,
                            int* __restrict__ pcnt,
                            uint16_t* __restrict__ zsA_dummy,
                            uint16_t* __restrict__ zsB_dummy, int n)
{
    int i = blockIdx.x * blockDim.x + threadIdx.x;
    if (i < n) {
        int c = cnt[i];
        dinv[i] = rsqrtf((float)c + 1.0f);  // +1 self-loop
        pcnt[i] = (c + 3) & ~3;
    }
    if (i < 16) { zsA_dummy[i] = 0; zsB_dummy[i] = 0; }
}

// fill csr pad region with the dummy node index
__global__ void fill_kernel(int4* __restrict__ p, int v, int cnt4)
{
    int i = blockIdx.x * blockDim.x + threadIdx.x;
    if (i < cnt4) p[i] = make_int4(v, v, v, v);
}

// multi-block exclusive scan over pcnt (3 phases), covers i <= n
__global__ __launch_bounds__(256) void scan1_kernel(
    const int* __restrict__ pcnt, int* __restrict__ row_loc,
    int* __restrict__ bsum, int n)
{
    __shared__ int sm[256];
    int i = blockIdx.x * 256 + threadIdx.x;
    int v = (i < n) ? pcnt[i] : 0;
    sm[threadIdx.x] = v;
    __syncthreads();
#pragma unroll
    for (int off = 1; off < 256; off <<= 1) {
        int t = (threadIdx.x >= off) ? sm[threadIdx.x - off] : 0;
        __syncthreads();
        sm[threadIdx.x] += t;
        __syncthreads();
    }
    if (i <= n) row_loc[i] = sm[threadIdx.x] - v;
    if (threadIdx.x == 255) bsum[blockIdx.x] = sm[255];
}

__global__ __launch_bounds__(512) void scan2_kernel(
    const int* __restrict__ bsum, int* __restrict__ boff, int nb)
{
    __shared__ int sm[512];
    int i = threadIdx.x;
    int v = (i < nb) ? bsum[i] : 0;
    sm[i] = v;
    __syncthreads();
#pragma unroll
    for (int off = 1; off < 512; off <<= 1) {
        int t = (i >= off) ? sm[i - off] : 0;
        __syncthreads();
        sm[i] += t;
        __syncthreads();
    }
    if (i < nb) boff[i] = sm[i] - v;
}

__global__ void scan3_kernel(int* __restrict__ row_st, const int* __restrict__ boff,
                             int* __restrict__ cursor, int n)
{
    int i = blockIdx.x * blockDim.x + threadIdx.x;
    if (i <= n) {
        int r = row_st[i] + boff[i >> 8];
        row_st[i] = r;
        if (i < n) cursor[i] = r;
    }
}

// ---------------------------------------------------------------------------
// XCD-windowed scatter: block b = chunk (b>>3) x dst-window (b&7).
// Writes only the 4B src index (dst implied by CSR row). Edge order within a
// row is nondeterministic (atomics) -- prop compensates with fp64 accum.
// ---------------------------------------------------------------------------
#define SC_CHUNK 2048
__global__ __launch_bounds__(256) void scatter8_kernel(
    const int* __restrict__ src, const int* __restrict__ dst,
    int* __restrict__ cursor, int* __restrict__ csr_s, int e)
{
    const int w    = blockIdx.x & 7;
    const int base = (blockIdx.x >> 3) * SC_CHUNK;
    const int wlo  = w * (N_NODES / 8);
    const int whi  = wlo + (N_NODES / 8);
#pragma unroll
    for (int t = 0; t < SC_CHUNK / 256; ++t) {
        int i = base + t * 256 + threadIdx.x;
        if (i < e) {
            int d = dst[i];
            if (d >= wlo && d < whi) {
                int s = src[i];
                int pos = atomicAdd(&cursor[d], 1);
                csr_s[pos] = s;
            }
        }
    }
}

// ---------------------------------------------------------------------------
// Node-parallel pull, 16 lanes/node, rows padded to mult-of-4.
// R8: zs state is bf16 (32B/node row) -> whole zs = 3.2MB < 4MB per-XCD L2,
// so the uniform-random gathers become L2-resident instead of L3-served,
// and bytes halve. Gathers stay coalesced: 4 class-lanes read 4 consecutive
// uint2 (8B) = one 32B row. fp64 accumulation keeps the sum order-independent.
// ---------------------------------------------------------------------------
__global__ __launch_bounds__(256) void prop_kernel(
    const int* __restrict__ csr_s, const int* __restrict__ row_st,
    const float* __restrict__ dinv, const uint16_t* __restrict__ zs_in,
    const float* __restrict__ hmat, uint16_t* __restrict__ out_z,
    float* __restrict__ out_f, int n, int is_last)
{
    const int t = threadIdx.x;
    const int d = blockIdx.x * 16 + (t >> 4);
    if (d >= n) return;
    const int lane16 = t & 15;
    const int sub = lane16 >> 2;
    const int f4 = (lane16 & 3) * 4;
    const int rs = row_st[d], re = row_st[d + 1];

    // early-issued epilogue loads (latency hidden under the edge loop)
    const float di = dinv[d];
    const uint2 selfp = *(const uint2*)(zs_in + (size_t)d * 16 + f4);
    const float4 hv   = *(const float4*)(hmat + (size_t)d * 16 + f4);

    // self-loop contribution seeds sub 0's accumulator
    const double w0 = (sub == 0) ? 1.0 : 0.0;
    double Sx = w0 * (double)blo(selfp.x), Sy = w0 * (double)bhi(selfp.x);
    double Sz = w0 * (double)blo(selfp.y), Sw = w0 * (double)bhi(selfp.y);

    int j = rs + sub * 4;
    for (; j + 16 < re; j += 32) {
        int4 s0 = *(const int4*)(csr_s + j);
        int4 s1 = *(const int4*)(csr_s + j + 16);
        const uint2 a0 = *(const uint2*)(zs_in + (size_t)s0.x * 16 + f4);
        const uint2 b0 = *(const uint2*)(zs_in + (size_t)s0.y * 16 + f4);
        const uint2 c0 = *(const uint2*)(zs_in + (size_t)s0.z * 16 + f4);
        const uint2 e0 = *(const uint2*)(zs_in + (size_t)s0.w * 16 + f4);
        const uint2 a1 = *(const uint2*)(zs_in + (size_t)s1.x * 16 + f4);
        const uint2 b1 = *(const uint2*)(zs_in + (size_t)s1.y * 16 + f4);
        const uint2 c1 = *(const uint2*)(zs_in + (size_t)s1.z * 16 + f4);
        const uint2 e1 = *(const uint2*)(zs_in + (size_t)s1.w * 16 + f4);
        Sx += ((double)blo(a0.x) + (double)blo(b0.x)) + ((double)blo(c0.x) + (double)blo(e0.x))
            + ((double)blo(a1.x) + (double)blo(b1.x)) + ((double)blo(c1.x) + (double)blo(e1.x));
        Sy += ((double)bhi(a0.x) + (double)bhi(b0.x)) + ((double)bhi(c0.x) + (double)bhi(e0.x))
            + ((double)bhi(a1.x) + (double)bhi(b1.x)) + ((double)bhi(c1.x) + (double)bhi(e1.x));
        Sz += ((double)blo(a0.y) + (double)blo(b0.y)) + ((double)blo(c0.y) + (double)blo(e0.y))
            + ((double)blo(a1.y) + (double)blo(b1.y)) + ((double)blo(c1.y) + (double)blo(e1.y));
        Sw += ((double)bhi(a0.y) + (double)bhi(b0.y)) + ((double)bhi(c0.y) + (double)bhi(e0.y))
            + ((double)bhi(a1.y) + (double)bhi(b1.y)) + ((double)bhi(c1.y) + (double)bhi(e1.y));
    }
    if (j < re) {
        int4 s0 = *(const int4*)(csr_s + j);
        const uint2 a0 = *(const uint2*)(zs_in + (size_t)s0.x * 16 + f4);
        const uint2 b0 = *(const uint2*)(zs_in + (size_t)s0.y * 16 + f4);
        const uint2 c0 = *(const uint2*)(zs_in + (size_t)s0.z * 16 + f4);
        const uint2 e0 = *(const uint2*)(zs_in + (size_t)s0.w * 16 + f4);
        Sx += ((double)blo(a0.x) + (double)blo(b0.x)) + ((double)blo(c0.x) + (double)blo(e0.x));
        Sy += ((double)bhi(a0.x) + (double)bhi(b0.x)) + ((double)bhi(c0.x) + (double)bhi(e0.x));
        Sz += ((double)blo(a0.y) + (double)blo(b0.y)) + ((double)blo(c0.y) + (double)blo(e0.y));
        Sw += ((double)bhi(a0.y) + (double)bhi(b0.y)) + ((double)bhi(c0.y) + (double)bhi(e0.y));
    }

    // combine the 4 sub partial sums (all 16 lanes end with the full sum)
    Sx += __shfl_xor(Sx, 4); Sy += __shfl_xor(Sy, 4);
    Sz += __shfl_xor(Sz, 4); Sw += __shfl_xor(Sw, 4);
    Sx += __shfl_xor(Sx, 8); Sy += __shfl_xor(Sy, 8);
    Sz += __shfl_xor(Sz, 8); Sw += __shfl_xor(Sw, 8);

    float4 S = make_float4((float)Sx, (float)Sy, (float)Sz, (float)Sw);

    float4 zn;
    zn.x = fmaf(1.0f - ALPHA, di * S.x, ALPHA * hv.x);
    zn.y = fmaf(1.0f - ALPHA, di * S.y, ALPHA * hv.y);
    zn.z = fmaf(1.0f - ALPHA, di * S.z, ALPHA * hv.z);
    zn.w = fmaf(1.0f - ALPHA, di * S.w, ALPHA * hv.w);
    if (!is_last) {
        if (sub == 0) {
            uint32_t p0 = bf16_rne(di * zn.x) | (bf16_rne(di * zn.y) << 16);
            uint32_t p1 = bf16_rne(di * zn.z) | (bf16_rne(di * zn.w) << 16);
            *(uint2*)(out_z + (size_t)d * 16 + f4) = make_uint2(p0, p1);
        }
    } else {
        float m = fmaxf(fmaxf(zn.x, zn.y), fmaxf(zn.z, zn.w));
        m = fmaxf(m, __shfl_xor(m, 1));
        m = fmaxf(m, __shfl_xor(m, 2));
        float ss = expf(zn.x - m) + expf(zn.y - m) + expf(zn.z - m) + expf(zn.w - m);
        ss += __shfl_xor(ss, 1);
        ss += __shfl_xor(ss, 2);
        float ls = logf(ss);
        if (sub == 0)
            *(float4*)(out_f + (size_t)d * 16 + f4) =
                make_float4(zn.x - m - ls, zn.y - m - ls, zn.z - m - ls, zn.w - m - ls);
    }
}

// ---------------------------------------------------------------------------
extern "C" void kernel_launch(void* const* d_in, const int* in_sizes, int n_in,
                              void* d_out, int out_size, void* d_ws, size_t ws_size,
                              hipStream_t stream)
{
    const float* x  = (const float*)d_in[0];
    const float* W1 = (const float*)d_in[1];
    const float* b1 = (const float*)d_in[2];
    const float* W2 = (const float*)d_in[3];
    const float* b2 = (const float*)d_in[4];
    const int*   ei = (const int*)d_in[5];

    const int N = N_NODES;
    const int E = N_EDGES;
    const int EP_MAX = 3500000;                 // >= E + 3*N worst-case padded (pad-4)
    const int* srcp = ei;
    const int* dstp = ei + E;

    float* ws = (float*)d_ws;
    float*    h      = ws;                          // 1,600,000 f
    uint16_t* ZSA    = (uint16_t*)(ws + 1600000);   // 1,600,016 bf16 (= 800,008 f)
    uint16_t* ZSB    = (uint16_t*)(ws + 2400008);   // 1,600,016 bf16 (starts as hs)
    float*    dinv   = ws + 3200016;                // 100,000 f
    int*      row_st = (int*)(ws + 3300016);        // 100,001 i (pad 100004)
    int*      csr_s  = (int*)(ws + 3400020);        // up to 3,500,000 x 4B
    // transient overlays (dead before mlp writes h):
    int*   cnt     = (int*)(ws);                // 100,000
    int*   cursor  = (int*)(ws + 100000);       // 100,000
    int*   bsum    = (int*)(ws + 200000);       // 512
    int*   boff    = (int*)(ws + 200512);       // 512
    int*   pcnt    = (int*)(ws + 201024);       // 100,000
    uint4* W1f     = (uint4*)(ws + 1600000);    // in ZSA region (dead before step 0)
    uint16_t* zsA_dummy = ZSA + (size_t)N * 16;
    uint16_t* zsB_dummy = ZSB + (size_t)N * 16;

    const int NB_SCAN = (N + 255) / 256;        // 391 (covers i <= N)

    hipMemsetAsync(cnt, 0, (size_t)N * sizeof(int), stream);
    hist_kernel<<<(E + 255) / 256, 256, 0, stream>>>(dstp, cnt, E);
    dinv_kernel<<<(N + 255) / 256, 256, 0, stream>>>(cnt, dinv, pcnt,
                                                     zsA_dummy, zsB_dummy, N);
    fill_kernel<<<(EP_MAX / 4 + 255) / 256, 256, 0, stream>>>((int4*)csr_s, N, EP_MAX / 4);
    scan1_kernel<<<NB_SCAN, 256, 0, stream>>>(pcnt, row_st, bsum, N);
    scan2_kernel<<<1, 512, 0, stream>>>(bsum, boff, NB_SCAN);
    scan3_kernel<<<(N + 256) / 256, 256, 0, stream>>>(row_st, boff, cursor, N);
    {
        const int nchunks = (E + SC_CHUNK - 1) / SC_CHUNK;   // 1563
        scatter8_kernel<<<nchunks * 8, 256, 0, stream>>>(srcp, dstp, cursor, csr_s, E);
    }
    w1_frag_kernel<<<64, 256, 0, stream>>>(W1, W1f);
    mlp_kernel<<<(N + 63) / 64, 256, 0, stream>>>(x, W1f, b1, W2, b2, dinv, h, ZSB, N);

    const int NB_PROP = (N + 15) / 16;   // 6250 blocks, 16 nodes/block
    for (int k = 0; k < 10; ++k) {
        const int last = (k == 9) ? 1 : 0;
        const uint16_t* zin = (k == 0) ? ZSB : ((k & 1) ? ZSA : ZSB);
        uint16_t* zo = (k & 1) ? ZSB : ZSA;
        prop_kernel<<<NB_PROP, 256, 0, stream>>>(csr_s, row_st, dinv, zin, h, zo,
                                                 (float*)d_out, N, last);
    }
}